// Round 1
// baseline (143.204 us; speedup 1.0000x reference)
//
#include <hip/hip_runtime.h>

// GnnLayer: out[50000,64] = leaky_relu((h[idx]/dist).reshape(N,2048) @ W + bias)
// Strategy: bf16 MFMA GEMM (16x16x32) with gathered+scaled A, fp32 accumulate.
// ws layout: [0, 256KB) = W^T bf16 [64][2048]; [256KB, +6.4MB) = h bf16 [50000][64]

#define N_NODES 50000
#define KN      32
#define FIN     64
#define FOUT    64
#define KDIM    2048   // KN*FIN
#define MTILE   64

typedef __attribute__((ext_vector_type(4))) float f32x4;
typedef __attribute__((ext_vector_type(8))) short bf16x8;

static __device__ __forceinline__ unsigned short f2b(float f) {
    union { float f; unsigned int u; } v; v.f = f;
    unsigned int u = v.u;
    unsigned int r = (u + 0x7fffu + ((u >> 16) & 1u)) >> 16;  // RNE
    return (unsigned short)r;
}
static __device__ __forceinline__ float b2f(unsigned short b) {
    union { unsigned int u; float f; } v; v.u = ((unsigned int)b) << 16;
    return v.f;
}

// h (fp32, N*64) -> bf16. 800000 threads x 4 elems.
__global__ void k_conv_h(const float* __restrict__ src, unsigned short* __restrict__ dst) {
    int i = blockIdx.x * blockDim.x + threadIdx.x;
    float4 v = ((const float4*)src)[i];
    ushort4 p;
    p.x = f2b(v.x); p.y = f2b(v.y); p.z = f2b(v.z); p.w = f2b(v.w);
    ((ushort4*)dst)[i] = p;
}

// W[2048][64] fp32 -> W^T[64][2048] bf16 (so B-fragments are contiguous 16B).
__global__ void k_conv_w(const float* __restrict__ w, unsigned short* __restrict__ wt) {
    int i = blockIdx.x * blockDim.x + threadIdx.x;  // 131072 threads
    int kidx = i >> 6, n = i & 63;
    wt[n * KDIM + kidx] = f2b(w[i]);
}

__global__ __launch_bounds__(256) void k_main(
        const unsigned short* __restrict__ hb,   // bf16 h [N][64]
        const float*          __restrict__ pos,  // [N][3]
        const int*            __restrict__ nidx, // [N][32]
        const unsigned short* __restrict__ wt,   // bf16 W^T [64][2048]
        const float*          __restrict__ bias, // [64]
        float*                __restrict__ out)  // [N][64]
{
    __shared__ int            s_idx[MTILE * KN];   // 8 KB
    __shared__ float          s_scl[MTILE * KN];   // 8 KB
    __shared__ unsigned short sA[MTILE * 32];      // 4 KB: A-tile [m][k]
    __shared__ unsigned short sB[FOUT * 32];       // 4 KB: B-tile [n][k]

    const int tid = threadIdx.x;
    const int m0  = blockIdx.x * MTILE;

    // Phase 0: neighbor indices + 1/dist scales for this block's 64 nodes.
    for (int p = tid; p < MTILE * KN; p += 256) {
        int m = p >> 5, k = p & 31;
        int node = m0 + m;
        int idx = 0; float scl = 0.f;
        if (node < N_NODES) {
            idx = nidx[node * KN + k];
            float dx = pos[node * 3 + 0] - pos[idx * 3 + 0];
            float dy = pos[node * 3 + 1] - pos[idx * 3 + 1];
            float dz = pos[node * 3 + 2] - pos[idx * 3 + 2];
            float sq = dx * dx + dy * dy + dz * dz;
            // ref: dist = (sq==0) ? 0.5 : sqrt(sq);  scale = 1/dist
            scl = (sq == 0.f) ? 2.0f : (1.0f / sqrtf(sq));
        }
        s_idx[p] = idx; s_scl[p] = scl;
    }
    __syncthreads();

    const int wv = tid >> 6, lane = tid & 63;
    const int lm = lane & 15, q = lane >> 4;
    const int rowA = tid >> 2, part = tid & 3;  // staging: 4 threads/row, 8 elems each

    f32x4 acc[4] = {};  // wave wv covers M rows [wv*16,wv*16+16) x all 64 N cols

    for (int kk = 0; kk < KDIM / 32; ++kk) {
        const int kn = kk >> 1;          // neighbor slot
        const int j0 = (kk & 1) * 32;    // feature offset within neighbor
        // A-tile: gather h row slice, scale, bf16 -> LDS
        {
            int   idx = s_idx[rowA * KN + kn];
            float scl = s_scl[rowA * KN + kn];
            bf16x8 v = *(const bf16x8*)(hb + idx * FIN + j0 + part * 8);
            unsigned short o[8];
            #pragma unroll
            for (int e = 0; e < 8; ++e)
                o[e] = f2b(b2f(((unsigned short*)&v)[e]) * scl);
            *(bf16x8*)(sA + rowA * 32 + part * 8) = *(bf16x8*)o;
        }
        // B-tile: W^T slice -> LDS (n-major, k contiguous)
        {
            bf16x8 v = *(const bf16x8*)(wt + rowA * KDIM + kk * 32 + part * 8);
            *(bf16x8*)(sB + rowA * 32 + part * 8) = v;
        }
        __syncthreads();
        bf16x8 a = *(const bf16x8*)(sA + (wv * 16 + lm) * 32 + q * 8);
        #pragma unroll
        for (int t = 0; t < 4; ++t) {
            bf16x8 b = *(const bf16x8*)(sB + (t * 16 + lm) * 32 + q * 8);
            acc[t] = __builtin_amdgcn_mfma_f32_16x16x32_bf16(a, b, acc[t], 0, 0, 0);
        }
        __syncthreads();
    }

    // Epilogue: bias + leaky_relu(0.01). C/D: col=lane&15, row=q*4+reg.
    #pragma unroll
    for (int t = 0; t < 4; ++t) {
        int f = t * 16 + lm;
        float bs = bias[f];
        #pragma unroll
        for (int r = 0; r < 4; ++r) {
            int node = m0 + wv * 16 + q * 4 + r;
            if (node < N_NODES) {
                float v = acc[t][r] + bs;
                out[node * FOUT + f] = v > 0.f ? v : 0.01f * v;
            }
        }
    }
}

extern "C" void kernel_launch(void* const* d_in, const int* in_sizes, int n_in,
                              void* d_out, int out_size, void* d_ws, size_t ws_size,
                              hipStream_t stream) {
    const float* h    = (const float*)d_in[0];
    const float* pos  = (const float*)d_in[1];
    const int*   nidx = (const int*)d_in[2];
    const float* w    = (const float*)d_in[3];
    const float* bias = (const float*)d_in[4];
    float* out = (float*)d_out;

    unsigned short* wt = (unsigned short*)d_ws;                    // 256 KB
    unsigned short* hb = (unsigned short*)((char*)d_ws + 262144);  // 6.4 MB

    k_conv_w<<<(KDIM * FOUT) / 256, 256, 0, stream>>>(w, wt);
    k_conv_h<<<(N_NODES * FIN / 4) / 256, 256, 0, stream>>>(h, hb);
    k_main<<<(N_NODES + MTILE - 1) / MTILE, 256, 0, stream>>>(hb, pos, nidx, wt, bias, out);
}